// Round 5
// baseline (146.748 us; speedup 1.0000x reference)
//
#include <hip/hip_runtime.h>

#define BATCH 4
#define SEQ   4096
#define DIM   1024
#define EPS_F 1e-6f
#define KSPLIT 4

typedef __bf16 bf16_t;
typedef bf16_t bf16x8 __attribute__((ext_vector_type(8)));
typedef float  f32x4  __attribute__((ext_vector_type(4)));
typedef unsigned short u16x8 __attribute__((ext_vector_type(8)));

__device__ __forceinline__ unsigned short f2bf(float f) {
  unsigned u = __float_as_uint(f);
  u += 0x7FFFu + ((u >> 16) & 1u);          // round-to-nearest-even
  return (unsigned short)(u >> 16);
}
__device__ __forceinline__ float bf2f(unsigned short h) {
  return __uint_as_float(((unsigned)h) << 16);
}
__device__ __forceinline__ float phi_f(float x) {
  return x > 0.f ? x + 1.f : __expf(x);     // elu(x)+1
}

__global__ __launch_bounds__(256) void zero_f32(float* __restrict__ p, int n) {
  const int i = blockIdx.x * 256 + threadIdx.x;
  if (i < n) p[i] = 0.f;
}

// ---- transpose (+ optional phi, optional fused column-sum) ----
template<bool PHI, bool KSUM>
__global__ __launch_bounds__(256) void phi_transpose(const float* __restrict__ in,
    unsigned short* __restrict__ out, float* __restrict__ ksum, int rows, int cols) {
  __shared__ float t[32][33];
  __shared__ float ps[8][32];
  const int bx = blockIdx.x * 32;          // col base
  const int by = blockIdx.y * 32;          // row base
  const size_t bo = (size_t)blockIdx.z * rows * cols;
  const int x = threadIdx.x, y = threadIdx.y;
  #pragma unroll
  for (int j = 0; j < 32; j += 8) {
    float v = in[bo + (size_t)(by + y + j) * cols + bx + x];
    if (PHI) v = phi_f(v);
    t[y + j][x] = v;
  }
  __syncthreads();
  #pragma unroll
  for (int j = 0; j < 32; j += 8)
    out[bo + (size_t)(bx + y + j) * rows + by + x] = f2bf(t[x][y + j]);
  if (KSUM) {
    float s = t[y][x] + t[y + 8][x] + t[y + 16][x] + t[y + 24][x];
    ps[y][x] = s;
    __syncthreads();
    if (y == 0) {
      float tot = 0.f;
      #pragma unroll
      for (int j = 0; j < 8; ++j) tot += ps[j][x];
      atomicAdd(&ksum[(size_t)blockIdx.z * cols + bx + x], tot);
    }
  }
}

// ---- phi(Q) cast + fused Z ----
__global__ __launch_bounds__(256) void phi_cast_qz(const float* __restrict__ Q,
    const float* __restrict__ Ksum, unsigned short* __restrict__ Qp,
    float* __restrict__ invZ) {
  const int row  = blockIdx.x * 4 + (threadIdx.x >> 6);   // b*SEQ + n
  const int lane = threadIdx.x & 63;
  const int b = row >> 12;
  const float* q  = Q + (size_t)row * DIM;
  const float* ks = Ksum + (size_t)b * DIM;
  float s = 0.f;
  #pragma unroll
  for (int c = 0; c < 2; ++c) {
    const int d0 = c * 512 + lane * 8;
    float4 v0 = *(const float4*)(q + d0);
    float4 v1 = *(const float4*)(q + d0 + 4);
    float4 k0 = *(const float4*)(ks + d0);
    float4 k1 = *(const float4*)(ks + d0 + 4);
    u16x8 o;
    o[0] = f2bf(phi_f(v0.x)); s += bf2f(o[0]) * k0.x;
    o[1] = f2bf(phi_f(v0.y)); s += bf2f(o[1]) * k0.y;
    o[2] = f2bf(phi_f(v0.z)); s += bf2f(o[2]) * k0.z;
    o[3] = f2bf(phi_f(v0.w)); s += bf2f(o[3]) * k0.w;
    o[4] = f2bf(phi_f(v1.x)); s += bf2f(o[4]) * k1.x;
    o[5] = f2bf(phi_f(v1.y)); s += bf2f(o[5]) * k1.y;
    o[6] = f2bf(phi_f(v1.z)); s += bf2f(o[6]) * k1.z;
    o[7] = f2bf(phi_f(v1.w)); s += bf2f(o[7]) * k1.w;
    *(u16x8*)(Qp + (size_t)row * DIM + d0) = o;
  }
  #pragma unroll
  for (int off = 32; off > 0; off >>= 1) s += __shfl_down(s, off);
  if (lane == 0) invZ[row] = 1.0f / (s + EPS_F);
}

// ---- reduce KSPLIT bf16 partials -> bf16 KVt ----
__global__ __launch_bounds__(256) void reduce_kv(const unsigned short* __restrict__ P,
    unsigned short* __restrict__ KVt) {
  const size_t per = (size_t)DIM * DIM;
  const size_t i = ((size_t)blockIdx.x * 256 + threadIdx.x) * 8;
  const size_t b = blockIdx.y;
  const unsigned short* p = P + b * KSPLIT * per + i;
  float s[8] = {};
  #pragma unroll
  for (int sp = 0; sp < KSPLIT; ++sp) {
    u16x8 v = *(const u16x8*)(p + sp * per);
    #pragma unroll
    for (int j = 0; j < 8; ++j) s[j] += bf2f(v[j]);
  }
  u16x8 o;
  #pragma unroll
  for (int j = 0; j < 8; ++j) o[j] = f2bf(s[j]);
  *(u16x8*)(KVt + b * per + i) = o;
}

// ======== 256x256 8-phase bt-GEMM, fragment reads pipelined 1 phase ahead ====
// C[M][Nc] = A[M][K] * Bm[Nc][K]^T. 512 thr = 8 waves (2M x 4N), BK=64,
// dbuf LDS 128KB. Per K-tile t (4 phases), QUAD q consumes frags read in
// phase q-1; stage pieces of tile t+2 overwrite tile t's already-consumed
// regions; one vmcnt(6) per K-tile at ph2 (lands {AY_t,AX_t+1,BX_t+1,BY_t+1}).
#define GLD(gp, lp) __builtin_amdgcn_global_load_lds( \
    (const __attribute__((address_space(1))) unsigned int*)(gp), \
    (__attribute__((address_space(3))) unsigned int*)(lp), 16, 0, 0)
#define BARRIER __builtin_amdgcn_s_barrier()
#define WAITV(n) asm volatile("s_waitcnt vmcnt(" #n ")" ::: "memory")

template<int EPI, int KS, int NT>
__global__ __launch_bounds__(512, 2) void gemm256_bt(
    const unsigned short* __restrict__ A, const unsigned short* __restrict__ Bm,
    void* __restrict__ Cv, const float* __restrict__ invZ,
    int M, int Nc, int K, int gx, int gy) {
  extern __shared__ unsigned short lds[];
  unsigned short* const As0 = lds;
  unsigned short* const As1 = lds + 16384;
  unsigned short* const Bs0 = lds + 32768;
  unsigned short* const Bs1 = lds + 49152;

  const int t    = threadIdx.x;
  const int wid  = t >> 6;
  const int lane = t & 63;
  // XCD-chunked bijective swizzle (gridDim.x divisible by 8)
  const int id   = blockIdx.x;
  const int sw   = (id & 7) * (gridDim.x >> 3) + (id >> 3);
  const int bxi  = sw % gx;
  const int rem  = sw / gx;
  const int byi  = rem % gy;
  const int bz   = rem / gy;
  const int brow = byi * 256, bcol = bxi * 256;
  const size_t batch = bz / KS;
  const int split = bz % KS;
  const int Kc = K / KS;
  const unsigned short* Ab = A + batch * ((size_t)M * K) + (size_t)brow * K + (size_t)split * Kc;
  const unsigned short* Bb = Bm + batch * ((size_t)Nc * K) + (size_t)bcol * K + (size_t)split * Kc;

  // staging: thread t -> row t>>3, chunk t&7 (linear LDS dest); global chunk
  // pre-swizzled with row&7.
  const int srow_t = t >> 3;                       // 0..63
  const int c_src  = (t & 7) ^ (srow_t & 7);
  const unsigned short* gA = Ab + (size_t)srow_t * K + c_src * 8;
  const unsigned short* gB = Bb + (size_t)((srow_t >> 5) * 64 + (srow_t & 31)) * K + c_src * 8;
  const int ldsAu = wid * 512;                          // wave-uniform LDS base (elems)
  const int ldsBu = wid * 512 + (wid >> 2) * 2048;

  auto stageA = [&](unsigned short* D, int h, int kt) {
    GLD(gA + (size_t)(h * 64) * K + (size_t)kt * 64,       D + (h * 64) * 64 + ldsAu);
    GLD(gA + (size_t)(128 + h * 64) * K + (size_t)kt * 64, D + (128 + h * 64) * 64 + ldsAu);
  };
  auto stageB = [&](unsigned short* D, int h, int kt) {
    GLD(gB + (size_t)(h * 32) * K + (size_t)kt * 64,       D + (h * 32) * 64 + ldsBu);
    GLD(gB + (size_t)(128 + h * 32) * K + (size_t)kt * 64, D + (128 + h * 32) * 64 + ldsBu);
  };

  const int fr  = lane & 15;
  const int g   = lane >> 4;
  const int wrw = (wid >> 2) * 128;          // wave row base (2 M-groups)
  const int wcw = (wid & 3) * 64;            // wave col base (4 N-groups)
  const int ck0 = ((g)     ^ (fr & 7)) * 8;  // kk=0 swizzled chunk (elems)
  const int ck1 = ((4 + g) ^ (fr & 7)) * 8;  // kk=1

  f32x4 acc[8][4] = {};
  bf16x8 afX[4][2], afY[4][2], bfX[2][2], bfY[2][2];

#define LDA(S, mh, DST) { _Pragma("unroll") for (int m_ = 0; m_ < 4; ++m_) { \
    const int ro_ = (wrw + ((mh) * 4 + m_) * 16 + fr) * 64; \
    DST[m_][0] = *(const bf16x8*)((S) + ro_ + ck0); \
    DST[m_][1] = *(const bf16x8*)((S) + ro_ + ck1); } }
#define LDBF(S, nh, DST) { _Pragma("unroll") for (int n_ = 0; n_ < 2; ++n_) { \
    const int ro_ = (wcw + (nh) * 32 + n_ * 16 + fr) * 64; \
    DST[n_][0] = *(const bf16x8*)((S) + ro_ + ck0); \
    DST[n_][1] = *(const bf16x8*)((S) + ro_ + ck1); } }
#define MM(mh, nh, AF, BF) { __builtin_amdgcn_s_setprio(1); \
    _Pragma("unroll") for (int m_ = 0; m_ < 4; ++m_) \
    _Pragma("unroll") for (int n_ = 0; n_ < 2; ++n_) \
    _Pragma("unroll") for (int k_ = 0; k_ < 2; ++k_) \
      acc[(mh) * 4 + m_][(nh) * 2 + n_] = __builtin_amdgcn_mfma_f32_16x16x32_bf16( \
          AF[m_][k_], BF[n_][k_], acc[(mh) * 4 + m_][(nh) * 2 + n_], 0, 0, 0); \
    __builtin_amdgcn_s_setprio(0); }

  unsigned short *Ac = As0, *An = As1, *Bc = Bs0, *Bn = Bs1;

  // prologue: stage tiles 0 and 1 fully; wait tile 0; preload Q00_0 operands
  stageA(Ac, 0, 0); stageB(Bc, 0, 0); stageB(Bc, 1, 0); stageA(Ac, 1, 0);
  stageA(An, 0, 1); stageB(Bn, 0, 1); stageB(Bn, 1, 1);
  stageA(An, 1, 1);
  WAITV(8);
  BARRIER;
  LDA(Ac, 0, afX); LDBF(Bc, 0, bfX);

  #pragma unroll 1
  for (int it = 0; it < NT - 2; ++it) {
    const int t2 = it + 2;
    // ph1: read YB_t | stage AX_{t+2} (into Ac: region consumed ph(t-1,3))
    LDBF(Bc, 1, bfY);
    stageA(Ac, 0, t2);
    BARRIER; MM(0, 0, afX, bfX); BARRIER;
    // ph2: stage BX_{t+2} | vmcnt(6) lands {AY_t, AX_t+1, BX_t+1, BY_t+1}
    stageB(Bc, 0, t2);
    WAITV(6);
    BARRIER;
    LDA(Ac, 1, afY);               // read AFTER waitv+barrier (AY_t just landed)
    MM(0, 1, afX, bfY); BARRIER;
    // ph3: read AX_{t+1} from other buffer | stage BY_{t+2}
    LDA(An, 0, afX);
    stageB(Bc, 1, t2);
    BARRIER; MM(1, 0, afY, bfX); BARRIER;
    // ph4: read BX_{t+1} | stage AY_{t+2}
    LDBF(Bn, 0, bfX);
    stageA(Ac, 1, t2);
    BARRIER; MM(1, 1, afY, bfY); BARRIER;
    unsigned short* tp;
    tp = Ac; Ac = An; An = tp;
    tp = Bc; Bc = Bn; Bn = tp;
  }
  // tail tile NT-2: no staging; drain all loads at ph2
  LDBF(Bc, 1, bfY);
  BARRIER; MM(0, 0, afX, bfX); BARRIER;
  WAITV(0);
  BARRIER;
  LDA(Ac, 1, afY);
  MM(0, 1, afX, bfY); BARRIER;
  LDA(An, 0, afX);
  BARRIER; MM(1, 0, afY, bfX); BARRIER;
  LDBF(Bn, 0, bfX);
  BARRIER; MM(1, 1, afY, bfY); BARRIER;
  {
    unsigned short* tp;
    tp = Ac; Ac = An; An = tp;
    tp = Bc; Bc = Bn; Bn = tp;
  }
  // tail tile NT-1
  LDBF(Bc, 1, bfY);
  BARRIER; MM(0, 0, afX, bfX);
  LDA(Ac, 1, afY);
  MM(0, 1, afX, bfY);
  MM(1, 0, afY, bfX);
  MM(1, 1, afY, bfY);
#undef LDA
#undef LDBF
#undef MM

  // epilogue: C/D layout col=fr, row=g*4+r per 16x16 fragment
  if (EPI == 0) {
    unsigned short* Cb = (unsigned short*)Cv + (size_t)bz * M * Nc;
    #pragma unroll
    for (int m = 0; m < 8; ++m) {
      const int row = brow + wrw + m * 16 + g * 4;
      #pragma unroll
      for (int r = 0; r < 4; ++r)
        #pragma unroll
        for (int n = 0; n < 4; ++n)
          Cb[(size_t)(row + r) * Nc + bcol + wcw + n * 16 + fr] = f2bf(acc[m][n][r]);
    }
  } else {
    float* Cb = (float*)Cv + batch * ((size_t)M * Nc);
    const float* zb = invZ + batch * (size_t)M;
    #pragma unroll
    for (int m = 0; m < 8; ++m) {
      const int row = brow + wrw + m * 16 + g * 4;
      #pragma unroll
      for (int r = 0; r < 4; ++r) {
        const float z = zb[row + r];
        #pragma unroll
        for (int n = 0; n < 4; ++n)
          Cb[(size_t)(row + r) * Nc + bcol + wcw + n * 16 + fr] = acc[m][n][r] * z;
      }
    }
  }
}

extern "C" void kernel_launch(void* const* d_in, const int* in_sizes, int n_in,
                              void* d_out, int out_size, void* d_ws, size_t ws_size,
                              hipStream_t stream) {
  const float* Q = (const float*)d_in[0];
  const float* K = (const float*)d_in[1];
  const float* V = (const float*)d_in[2];
  float* out = (float*)d_out;

  char* ws = (char*)d_ws;
  size_t off = 0;
  auto alloc = [&](size_t bytes) {
    void* p = ws + off;
    off += (bytes + 255) & ~(size_t)255;
    return p;
  };
  unsigned short* Qp   = (unsigned short*)alloc((size_t)BATCH * SEQ * DIM * 2);
  unsigned short* P    = Qp;  // split-K partials [B][KSPLIT][DIM*DIM] bf16 = 32 MB
  unsigned short* Kt   = (unsigned short*)alloc((size_t)BATCH * SEQ * DIM * 2);
  unsigned short* Vt   = (unsigned short*)alloc((size_t)BATCH * SEQ * DIM * 2);
  unsigned short* KVt  = (unsigned short*)alloc((size_t)BATCH * DIM * DIM * 2);
  float* Ksum = (float*)alloc((size_t)BATCH * DIM * 4);
  float* invZ = (float*)alloc((size_t)BATCH * SEQ * 4);

  hipFuncSetAttribute(reinterpret_cast<const void*>(&gemm256_bt<0, KSPLIT, 16>),
                      hipFuncAttributeMaxDynamicSharedMemorySize, 131072);
  hipFuncSetAttribute(reinterpret_cast<const void*>(&gemm256_bt<1, 1, 16>),
                      hipFuncAttributeMaxDynamicSharedMemorySize, 131072);

  const dim3 tb(32, 8);
  zero_f32<<<(BATCH * DIM + 255) / 256, 256, 0, stream>>>(Ksum, BATCH * DIM);
  phi_transpose<true, true ><<<dim3(DIM / 32, SEQ / 32, BATCH), tb, 0, stream>>>(K, Kt, Ksum, SEQ, DIM);
  phi_transpose<false, false><<<dim3(DIM / 32, SEQ / 32, BATCH), tb, 0, stream>>>(V, Vt, nullptr, SEQ, DIM);
  // gemm1 split-K: P[b][s] = Vt * Kt^T over n-split s   (M=Nc=1024, Kc=1024 -> NT=16)
  gemm256_bt<0, KSPLIT, 16><<<(DIM / 256) * (DIM / 256) * BATCH * KSPLIT, 512, 131072, stream>>>(
      Vt, Kt, P, nullptr, DIM, DIM, SEQ, DIM / 256, DIM / 256);
  reduce_kv<<<dim3(DIM * DIM / (256 * 8), BATCH), 256, 0, stream>>>(P, KVt);
  // phi(Q) cast + fused Z (after reduce: overwrites P region)
  phi_cast_qz<<<BATCH * SEQ / 4, 256, 0, stream>>>(Q, Ksum, Qp, invZ);
  // gemm2: out = (Qp * KVt^T) * invZ   (M=4096, Nc=1024, K=1024 -> NT=16)
  gemm256_bt<1, 1, 16><<<(DIM / 256) * (SEQ / 256) * BATCH, 512, 131072, stream>>>(
      Qp, KVt, out, invZ, SEQ, DIM, DIM, DIM / 256, SEQ / 256);
}